// Round 13
// baseline (214.642 us; speedup 1.0000x reference)
//
#include <hip/hip_runtime.h>
#include <math.h>

// Problem constants
constexpr int B = 8;
constexpr int D = 256;     // model dim
constexpr int C = 1024;    // expanded channels
constexpr int H = 32, W = 32;
constexpr int P = H * W;            // 1024 spatial positions
constexpr int M = B * P;            // 8192 rows
constexpr float EPS = 1e-5f;

typedef unsigned short u16;
typedef unsigned int u32;
typedef __attribute__((ext_vector_type(8))) short short8;
typedef __attribute__((ext_vector_type(4))) float floatx4;

// ---------------- workspace layout (in floats) ----------------
// zero-initialized accumulator region (zeroed by cvt kernel)
constexpr size_t WS_CHSUM1 = 0;                  // 1024
constexpr size_t WS_CHSQ1  = 1024;               // 1024
constexpr size_t WS_GAPSUM = 2048;               // 8192
constexpr size_t WS_CHSUM3 = 10240;              // 256
constexpr size_t WS_CHSQ3  = 10496;              // 256
constexpr size_t WS_CHSUM2 = 10752;              // 1024
constexpr size_t WS_CHSQ2  = 11776;              // 1024
constexpr size_t WS_BSUM2  = 12800;              // 8192
constexpr size_t WS_UMAX2  = 20992;              // 8192 (u32 keys)
constexpr size_t WS_UMAXN2 = 29184;              // 8192 (u32 keys of -min)
constexpr size_t WS_ACC_COUNT = 37376;
// non-zeroed
constexpr size_t WS_SCALE1 = 37376;              // 1024
constexpr size_t WS_SHIFT1 = 38400;              // 1024
constexpr size_t WS_KW     = 39424;              // 256 (72 used)
constexpr size_t WS_SCALE2 = 39680;              // 1024
constexpr size_t WS_SHIFT2 = 40704;              // 1024
constexpr size_t WS_SATT   = 41728;              // 8192
constexpr size_t WS_AVGO   = 49920;              // 8192
constexpr size_t WS_MAXO   = 58112;              // 8192
constexpr size_t WS_SP     = 66304;              // 8192 (unused now)
constexpr size_t WS_PRE    = 74496;              // 2097152
constexpr size_t WS_T1B    = 2171648;            // bf16 t1 (4194304 floats)
constexpr size_t WS_T2B    = 6365952;            // bf16 t2
constexpr size_t WS_XB     = 10560256;           // bf16 x
constexpr size_t WS_W1B    = 11608832;
constexpr size_t WS_PWB    = 11739904;
constexpr size_t WS_YB     = 11870976;           // bf16 y
// total = 16065280 floats = 64.3 MB

__device__ __forceinline__ float gelu_exact(float v) {
    return 0.5f * v * (1.0f + erff(v * 0.70710678118654752440f));
}

__device__ __forceinline__ u16 f2bf(float f) {
    u32 u = __float_as_uint(f);
    u += 0x7fff + ((u >> 16) & 1);   // round-to-nearest-even
    return (u16)(u >> 16);
}

__device__ __forceinline__ float bf2f(u16 v) {
    return __uint_as_float(((u32)v) << 16);
}

// order-preserving float->u32 key
__device__ __forceinline__ u32 fkey(float f) {
    u32 u = __float_as_uint(f);
    return (u & 0x80000000u) ? ~u : (u | 0x80000000u);
}
__device__ __forceinline__ float fkeyinv(u32 k) {
    return __uint_as_float((k & 0x80000000u) ? (k ^ 0x80000000u) : ~k);
}

// ---------------- K0: zero accumulators + cast fp32 -> bf16 for x, w1, pw ----------------
__global__ __launch_bounds__(256) void cvt_all_kernel(const float* __restrict__ x,
                                                      const float* __restrict__ w1,
                                                      const float* __restrict__ pw,
                                                      u16* __restrict__ xb,
                                                      u16* __restrict__ w1b,
                                                      u16* __restrict__ pwb,
                                                      float* __restrict__ acc_zero) {
    const int i = blockIdx.x * 256 + threadIdx.x;
    if (i < (int)WS_ACC_COUNT) acc_zero[i] = 0.f;
    const float* src;
    u16* dst;
    int off;
    if (i < 524288)      { src = x;  dst = xb;  off = i; }
    else if (i < 589824) { src = w1; dst = w1b; off = i - 524288; }
    else                 { src = pw; dst = pwb; off = i - 589824; }
    const float4 v = *(const float4*)(src + (size_t)off * 4);
    uint2 o;
    o.x = ((u32)f2bf(v.x)) | ((u32)f2bf(v.y) << 16);
    o.y = ((u32)f2bf(v.z)) | ((u32)f2bf(v.w) << 16);
    *(uint2*)(dst + (size_t)off * 4) = o;
}

// ---------------- K1: gemm1, full-K single-barrier staging ----------------
// 64x64 tile, K=256 entirely in LDS (8 chunks of [64 rows x 32 k], conflict-free layout).
// 16 global_load_lds -> ONE vmcnt drain -> 32 MFMA -> epilogue (bf16 LDS-staged stores).
// Fused: bias+GELU, BN1 col stats (chsum1/chsq1) + per-batch gapsum.
__global__ __launch_bounds__(256) void gemm1_kernel(
    const u16* __restrict__ A,      // xb (8192 x 256)
    const u16* __restrict__ Bw,     // w1b (1024 x 256)
    const float* __restrict__ bias,
    u16* __restrict__ outp_g,       // t1b (8192 x 1024)
    float* __restrict__ csum,
    float* __restrict__ csq,
    float* __restrict__ gsum)
{
    __shared__ u16 As[8 * 2048];    // 32 KB: [chunk][row*32+kk]
    __shared__ u16 Bs[8 * 2048];    // 32 KB
    const int t = threadIdx.x;
    const int lane = t & 63;
    const int wv = t >> 6;
    const int row0 = blockIdx.y * 64;
    const int col0 = blockIdx.x * 64;
    const int wrow = (wv >> 1) * 32;
    const int wcol = (wv & 1) * 32;
    const int lm = lane & 15;
    const int lk8 = (lane >> 4) * 8;
    const int srow = t >> 2;
    const int scol = (t & 3) * 8;

    const u16* gA = A + (size_t)(row0 + srow) * 256 + scol;
    const u16* gB = Bw + (size_t)(col0 + srow) * 256 + scol;
#pragma unroll
    for (int c = 0; c < 8; ++c) {
        __builtin_amdgcn_global_load_lds(
            (const __attribute__((address_space(1))) void*)(gA + c * 32),
            (__attribute__((address_space(3))) void*)(As + c * 2048 + t * 8), 16, 0, 0);
        __builtin_amdgcn_global_load_lds(
            (const __attribute__((address_space(1))) void*)(gB + c * 32),
            (__attribute__((address_space(3))) void*)(Bs + c * 2048 + t * 8), 16, 0, 0);
    }
    __syncthreads();   // the ONLY staging drain

    const floatx4 zero = {0.f, 0.f, 0.f, 0.f};
    floatx4 acc[2][2];
    acc[0][0] = zero; acc[0][1] = zero; acc[1][0] = zero; acc[1][1] = zero;
#pragma unroll
    for (int c = 0; c < 8; ++c) {
        short8 af[2], bf[2];
#pragma unroll
        for (int i = 0; i < 2; ++i)
            af[i] = *(const short8*)(As + c * 2048 + (wrow + i * 16 + lm) * 32 + lk8);
#pragma unroll
        for (int j = 0; j < 2; ++j)
            bf[j] = *(const short8*)(Bs + c * 2048 + (wcol + j * 16 + lm) * 32 + lk8);
#pragma unroll
        for (int i = 0; i < 2; ++i)
#pragma unroll
            for (int j = 0; j < 2; ++j)
                acc[i][j] = __builtin_amdgcn_mfma_f32_16x16x32_bf16(af[i], bf[j], acc[i][j], 0, 0, 0);
    }
    __syncthreads();   // all reads done before Cs aliases As

    // epilogue: bias+GELU, bf16 Cs staging, col stats
    u16* Cs = As;      // 64x64 u16 = 8 KB
    float colsum[2] = {0.f, 0.f}, colsq[2] = {0.f, 0.f};
#pragma unroll
    for (int i = 0; i < 2; ++i) {
#pragma unroll
        for (int r = 0; r < 4; ++r) {
            const int lrow = wrow + i * 16 + (lane >> 4) * 4 + r;
#pragma unroll
            for (int j = 0; j < 2; ++j) {
                const int lcol = wcol + j * 16 + lm;
                const float tv = gelu_exact(acc[i][j][r] + bias[col0 + lcol]);
                Cs[lrow * 64 + lcol] = f2bf(tv);
                colsum[j] += tv;
                colsq[j] = fmaf(tv, tv, colsq[j]);
            }
        }
    }
    __syncthreads();
    {
        const int rr = t >> 2;            // 0..63
        const int hh = (t & 3) * 16;      // u16 offset
        u16* op = outp_g + (size_t)(row0 + rr) * C + col0 + hh;
        *(uint4*)(op)     = *(const uint4*)(Cs + rr * 64 + hh);
        *(uint4*)(op + 8) = *(const uint4*)(Cs + rr * 64 + hh + 8);
    }
    const int bb = row0 >> 10;
#pragma unroll
    for (int j = 0; j < 2; ++j) {
        float s = colsum[j];
        float q = colsq[j];
        s += __shfl_xor(s, 16); s += __shfl_xor(s, 32);
        q += __shfl_xor(q, 16); q += __shfl_xor(q, 32);
        if (lane < 16) {
            const int c = col0 + wcol + j * 16 + lm;
            atomicAdd(&csum[c], s);
            atomicAdd(&csq[c], q);
            atomicAdd(&gsum[bb * C + c], s);
        }
    }
}

// ---------------- K4: dynamic kernel MLP + fused BN1 stats ----------------
__global__ __launch_bounds__(1024) void dynmlp_kernel(const float* __restrict__ chsum1,
                                                      const float* __restrict__ chsq1,
                                                      const float* __restrict__ gapsum,
                                                      const float* __restrict__ g1,
                                                      const float* __restrict__ be1,
                                                      const float* __restrict__ aw1,
                                                      const float* __restrict__ ab1,
                                                      const float* __restrict__ aw2,
                                                      const float* __restrict__ ab2,
                                                      float* __restrict__ scale1,
                                                      float* __restrict__ shift1,
                                                      float* __restrict__ kw) {
    const int b = blockIdx.x;
    const int t = threadIdx.x;
    const int wave = t >> 6, lane = t & 63;
    __shared__ float g[1024];
    __shared__ float h1[128];
    __shared__ float logits[12];
    {
        const float m = chsum1[t] * (1.0f / (float)M);
        const float var = chsq1[t] * (1.0f / (float)M) - m * m;
        const float rstd = rsqrtf(var + EPS);
        const float sc = rstd * g1[t];
        const float sh = be1[t] - m * sc;
        if (b == 0) { scale1[t] = sc; shift1[t] = sh; }
        g[t] = gapsum[b * C + t] * (1.0f / (float)P) * sc + sh;
    }
    __syncthreads();
#pragma unroll
    for (int k = 0; k < 8; ++k) {
        const int u = wave * 8 + k;
        const float4* wr = (const float4*)(aw1 + (size_t)u * C);
        float s = 0.f;
#pragma unroll
        for (int ch = 0; ch < 4; ++ch) {
            const float4 wv = wr[lane + 64 * ch];
            const float4 sv = *(const float4*)(g + 4 * lane + 256 * ch);
            s += wv.x * sv.x + wv.y * sv.y + wv.z * sv.z + wv.w * sv.w;
        }
#pragma unroll
        for (int off = 1; off < 64; off <<= 1) s += __shfl_xor(s, off);
        if (lane == 0) h1[u] = fmaxf(s + ab1[u], 0.f);
    }
    __syncthreads();
    if (wave < 9) {
        float s = aw2[wave * 128 + lane] * h1[lane]
                + aw2[wave * 128 + 64 + lane] * h1[64 + lane];
#pragma unroll
        for (int off = 1; off < 64; off <<= 1) s += __shfl_xor(s, off);
        if (lane == 0) logits[wave] = s + ab2[wave];
    }
    __syncthreads();
    if (t == 0) {
        float mx = logits[0];
        for (int i = 1; i < 9; ++i) mx = fmaxf(mx, logits[i]);
        float e[9], den = 0.f;
        for (int i = 0; i < 9; ++i) { e[i] = expf(logits[i] - mx); den += e[i]; }
        const float inv = 1.0f / den;
        for (int i = 0; i < 9; ++i) kw[b * 9 + i] = e[i] * inv;
    }
}

// ---------------- K5: dyn depthwise conv v3 — LDS-staged rows (R11-proven) ----------------
__global__ __launch_bounds__(256) void dwconv_kernel(const u16* __restrict__ t1b,
                                                     const float* __restrict__ scale1,
                                                     const float* __restrict__ shift1,
                                                     const float* __restrict__ kw,
                                                     u16* __restrict__ t2b,
                                                     float* __restrict__ chsum2,
                                                     float* __restrict__ chsq2,
                                                     float* __restrict__ bsum2,
                                                     u32* __restrict__ umax2,
                                                     u32* __restrict__ umaxn2) {
    __shared__ u16 rows[3 * 32 * 256];   // 48 KB: [r][w][ch]
    const int bh = blockIdx.y;
    const int b = bh >> 5;
    const int h = bh & 31;
    const int cq = blockIdx.x;
    const int t = threadIdx.x;

    const u16* gbase = t1b + (size_t)b * P * C + cq * 256;
#pragma unroll
    for (int i = 0; i < 12; ++i) {
        const int lin = i * 256 + t;
        const int chunk = lin >> 5;
        const int r = chunk >> 5;
        const int w = chunk & 31;
        const int off8 = (lin & 31) * 8;
        const int hr = h + r - 1;
        uint4 v = {0u, 0u, 0u, 0u};
        if (hr >= 0 && hr < H)
            v = *(const uint4*)(gbase + (size_t)(hr * W + w) * C + off8);
        *(uint4*)(&rows[chunk * 256 + off8]) = v;
    }
    __syncthreads();

    const int c = t;
    const int gc = cq * 256 + c;
    float k[9];
#pragma unroll
    for (int i = 0; i < 9; ++i) k[i] = kw[b * 9 + i];
    const float sc = scale1[gc];
    const float sh = shift1[gc];
    const bool rok[3] = { h > 0, true, h < H - 1 };

    float s = 0.f, q = 0.f, mx = -INFINITY, mn = INFINITY;
    for (int w = 0; w < W; ++w) {
        float acc = 0.f;
#pragma unroll
        for (int ri = 0; ri < 3; ++ri) {
            if (!rok[ri]) continue;
            const u16* rp = rows + (ri * 32) * 256 + c;
            if (w > 0)
                acc = fmaf(k[ri * 3 + 0], fmaf(bf2f(rp[(w - 1) * 256]), sc, sh), acc);
            acc = fmaf(k[ri * 3 + 1], fmaf(bf2f(rp[w * 256]), sc, sh), acc);
            if (w < W - 1)
                acc = fmaf(k[ri * 3 + 2], fmaf(bf2f(rp[(w + 1) * 256]), sc, sh), acc);
        }
        const float y = gelu_exact(acc);
        t2b[((size_t)b * P + h * W + w) * C + gc] = f2bf(y);
        s += y;
        q = fmaf(y, y, q);
        mx = fmaxf(mx, y);
        mn = fminf(mn, y);
    }
    atomicAdd(&chsum2[gc], s);
    atomicAdd(&chsq2[gc], q);
    atomicAdd(&bsum2[b * C + gc], s);
    atomicMax(&umax2[b * C + gc], fkey(mx));
    atomicMax(&umaxn2[b * C + gc], fkey(-mn));
}

// ---------------- K8: channel attention + O(1) BN2 finalize ----------------
__global__ __launch_bounds__(1024) void chatt_kernel(const float* __restrict__ chsum2,
                                                     const float* __restrict__ chsq2,
                                                     const float* __restrict__ bsum2,
                                                     const u32* __restrict__ umax2,
                                                     const u32* __restrict__ umaxn2,
                                                     const float* __restrict__ g2,
                                                     const float* __restrict__ be2,
                                                     const float* __restrict__ caw1,
                                                     const float* __restrict__ caw2,
                                                     float* __restrict__ scale2,
                                                     float* __restrict__ shift2,
                                                     float* __restrict__ s_att) {
    const int b = blockIdx.x;
    const int t = threadIdx.x;          // channel
    const int wave = t >> 6, lane = t & 63;
    __shared__ float la[1024], lx[1024], ha[64], hm[64];
    {
        const float m = chsum2[t] * (1.0f / (float)M);
        const float var = chsq2[t] * (1.0f / (float)M) - m * m;
        const float rstd = rsqrtf(var + EPS);
        const float sc = rstd * g2[t];
        const float sh = be2[t] - m * sc;
        if (b == 0) { scale2[t] = sc; shift2[t] = sh; }
        la[t] = bsum2[b * C + t] * (1.0f / (float)P) * sc + sh;
        const float mx = fkeyinv(umax2[b * C + t]);
        const float mn = -fkeyinv(umaxn2[b * C + t]);
        lx[t] = (sc >= 0.f ? mx : mn) * sc + sh;
    }
    __syncthreads();
#pragma unroll
    for (int k = 0; k < 8; ++k) {
        const int u = wave * 8 + k;
        const int row = u & 63;
        const float* src = (u < 64) ? la : lx;
        const float4* wr = (const float4*)(caw1 + (size_t)row * C);
        float s = 0.f;
#pragma unroll
        for (int ch = 0; ch < 4; ++ch) {
            const float4 wv = wr[lane + 64 * ch];
            const float4 sv = *(const float4*)(src + 4 * lane + 256 * ch);
            s += wv.x * sv.x + wv.y * sv.y + wv.z * sv.z + wv.w * sv.w;
        }
#pragma unroll
        for (int off = 1; off < 64; off <<= 1) s += __shfl_xor(s, off);
        if (lane == 0) {
            s = fmaxf(s, 0.f);
            if (u < 64) ha[row] = s; else hm[row] = s;
        }
    }
    __syncthreads();
    {
        const float4* w2 = (const float4*)(caw2 + (size_t)t * 64);
        float s = 0.f;
#pragma unroll
        for (int j = 0; j < 16; ++j) {
            const float4 wv = w2[j];
            s += wv.x * (ha[j * 4 + 0] + hm[j * 4 + 0]);
            s += wv.y * (ha[j * 4 + 1] + hm[j * 4 + 1]);
            s += wv.z * (ha[j * 4 + 2] + hm[j * 4 + 2]);
            s += wv.w * (ha[j * 4 + 3] + hm[j * 4 + 3]);
        }
        s_att[b * C + t] = 1.0f / (1.0f + expf(-s));
    }
}

// ---------------- K9: y = s_att*bn2(t2) -> bf16 yb + per-row avg/max ----------------
__global__ __launch_bounds__(256) void yq_kernel(const u16* __restrict__ t2b,
                                                 const float* __restrict__ scale2,
                                                 const float* __restrict__ shift2,
                                                 const float* __restrict__ s_att,
                                                 u16* __restrict__ yb,
                                                 float* __restrict__ avg_o,
                                                 float* __restrict__ max_o) {
    const int row = blockIdx.x;       // b*P + p
    const int b = row >> 10;
    const int t = threadIdx.x;
    const int c0 = t * 4;
    const uint2 vv = *(const uint2*)(t2b + (size_t)row * C + c0);
    const float v0 = bf2f((u16)(vv.x & 0xffff));
    const float v1 = bf2f((u16)(vv.x >> 16));
    const float v2 = bf2f((u16)(vv.y & 0xffff));
    const float v3 = bf2f((u16)(vv.y >> 16));
    const float4 sc = *(const float4*)(scale2 + c0);
    const float4 sh = *(const float4*)(shift2 + c0);
    const float4 sa = *(const float4*)(s_att + (size_t)b * C + c0);
    const float y0 = fmaf(v0, sc.x, sh.x) * sa.x;
    const float y1 = fmaf(v1, sc.y, sh.y) * sa.y;
    const float y2 = fmaf(v2, sc.z, sh.z) * sa.z;
    const float y3 = fmaf(v3, sc.w, sh.w) * sa.w;
    uint2 o;
    o.x = ((u32)f2bf(y0)) | ((u32)f2bf(y1) << 16);
    o.y = ((u32)f2bf(y2)) | ((u32)f2bf(y3) << 16);
    *(uint2*)(yb + (size_t)row * C + c0) = o;
    float s = (y0 + y1) + (y2 + y3);
    float mx = fmaxf(fmaxf(y0, y1), fmaxf(y2, y3));
#pragma unroll
    for (int off = 32; off > 0; off >>= 1) {
        s += __shfl_down(s, off);
        mx = fmaxf(mx, __shfl_down(mx, off));
    }
    __shared__ float ss[4], sm[4];
    const int wave = t >> 6, lane = t & 63;
    if (lane == 0) { ss[wave] = s; sm[wave] = mx; }
    __syncthreads();
    if (t == 0) {
        const float S = ss[0] + ss[1] + ss[2] + ss[3];
        const float Mx = fmaxf(fmaxf(sm[0], sm[1]), fmaxf(sm[2], sm[3]));
        avg_o[row] = S * (1.0f / (float)C);
        max_o[row] = Mx;
    }
}

// ---------------- K12: gemm2, K-unroll x4 dbuf + fused spatial-conv prologue ----------------
// 64x64 tile, K=1024 in 8 barrier-pairs (4 chunks per stage). Prologue computes this
// block's 64 sp values (7x7 conv over avg_o/max_o + sigmoid) into LDS.
// Epilogue: sp*acc + bias, fp32 LDS-staged stores, BN3 col stats.
__global__ __launch_bounds__(256) void gemm2_kernel(
    const u16* __restrict__ A,      // yb (8192 x 1024)
    const u16* __restrict__ Bw,     // pwb (256 x 1024)
    const float* __restrict__ bias, // pb
    const float* __restrict__ avg_o,
    const float* __restrict__ max_o,
    const float* __restrict__ sw,
    const float* __restrict__ sb,
    float* __restrict__ pre,
    float* __restrict__ csum,
    float* __restrict__ csq)
{
    __shared__ u16 smem[16384];     // 32 KB: As[4][2048] then Bs[4][2048]
    __shared__ float spl[64];
    __shared__ float wsh[98];
    const int t = threadIdx.x;
    const int lane = t & 63;
    const int wv = t >> 6;
    const int row0 = blockIdx.y * 64;
    const int col0 = blockIdx.x * 64;
    const int b = row0 >> 10;
    const int wrow = (wv >> 1) * 32;
    const int wcol = (wv & 1) * 32;
    const int lm = lane & 15;
    const int lk8 = (lane >> 4) * 8;
    const int srow = t >> 2;
    const int scol = (t & 3) * 8;

    // ---- fused spatial attention for this block's 64 rows ----
    if (t < 98) wsh[t] = sw[t];
    __syncthreads();
    if (t < 64) {
        const int p = (row0 + t) & 1023;
        const int h = p >> 5, w = p & 31;
        float acc = sb[0];
        const float* pa = avg_o + b * P;
        const float* pm = max_o + b * P;
#pragma unroll
        for (int i = 0; i < 7; ++i) {
            const int hh = h + i - 3;
            if (hh < 0 || hh >= H) continue;
#pragma unroll
            for (int j = 0; j < 7; ++j) {
                const int ww = w + j - 3;
                if (ww < 0 || ww >= W) continue;
                const int pidx = hh * W + ww;
                acc = fmaf(wsh[i * 7 + j], pa[pidx], acc);
                acc = fmaf(wsh[49 + i * 7 + j], pm[pidx], acc);
            }
        }
        spl[t] = 1.0f / (1.0f + expf(-acc));
    }
    // no barrier needed yet; spl read only after K-loop's barriers

    const u16* gA = A + (size_t)(row0 + srow) * C + scol;
    const u16* gB = Bw + (size_t)(col0 + srow) * C + scol;
    const floatx4 zero = {0.f, 0.f, 0.f, 0.f};
    floatx4 acc[2][2];
    acc[0][0] = zero; acc[0][1] = zero; acc[1][0] = zero; acc[1][1] = zero;

    for (int k0 = 0; k0 < C; k0 += 128) {
#pragma unroll
        for (int c = 0; c < 4; ++c) {
            __builtin_amdgcn_global_load_lds(
                (const __attribute__((address_space(1))) void*)(gA + k0 + c * 32),
                (__attribute__((address_space(3))) void*)(smem + c * 2048 + t * 8), 16, 0, 0);
            __builtin_amdgcn_global_load_lds(
                (const __attribute__((address_space(1))) void*)(gB + k0 + c * 32),
                (__attribute__((address_space(3))) void*)(smem + 8192 + c * 2048 + t * 8), 16, 0, 0);
        }
        __syncthreads();
#pragma unroll
        for (int c = 0; c < 4; ++c) {
            const u16* As = smem + c * 2048;
            const u16* Bs = smem + 8192 + c * 2048;
            short8 af[2], bf[2];
#pragma unroll
            for (int i = 0; i < 2; ++i)
                af[i] = *(const short8*)(As + (wrow + i * 16 + lm) * 32 + lk8);
#pragma unroll
            for (int j = 0; j < 2; ++j)
                bf[j] = *(const short8*)(Bs + (wcol + j * 16 + lm) * 32 + lk8);
#pragma unroll
            for (int i = 0; i < 2; ++i)
#pragma unroll
                for (int j = 0; j < 2; ++j)
                    acc[i][j] = __builtin_amdgcn_mfma_f32_16x16x32_bf16(af[i], bf[j], acc[i][j], 0, 0, 0);
        }
        __syncthreads();
    }

    // epilogue: sp*acc + bias, fp32 Cs staging (16 KB aliases smem), col stats
    float* Cs = (float*)smem;
    float colsum[2] = {0.f, 0.f}, colsq[2] = {0.f, 0.f};
#pragma unroll
    for (int i = 0; i < 2; ++i) {
#pragma unroll
        for (int r = 0; r < 4; ++r) {
            const int lrow = wrow + i * 16 + (lane >> 4) * 4 + r;
            const float rs = spl[lrow];
#pragma unroll
            for (int j = 0; j < 2; ++j) {
                const int lcol = wcol + j * 16 + lm;
                const float tv = rs * acc[i][j][r] + bias[col0 + lcol];
                Cs[lrow * 64 + lcol] = tv;
                colsum[j] += tv;
                colsq[j] = fmaf(tv, tv, colsq[j]);
            }
        }
    }
    __syncthreads();
    {
        const int rr = t >> 2;            // 0..63
        const int hh = (t & 3) * 16;      // float offset
        float* op = pre + (size_t)(row0 + rr) * D + col0 + hh;
#pragma unroll
        for (int k = 0; k < 4; ++k)
            *(float4*)(op + k * 4) = *(const float4*)(Cs + rr * 64 + hh + k * 4);
    }
#pragma unroll
    for (int j = 0; j < 2; ++j) {
        float s = colsum[j];
        float q = colsq[j];
        s += __shfl_xor(s, 16); s += __shfl_xor(s, 32);
        q += __shfl_xor(q, 16); q += __shfl_xor(q, 32);
        if (lane < 16) {
            const int c = col0 + wcol + j * 16 + lm;
            atomicAdd(&csum[c], s);
            atomicAdd(&csq[c], q);
        }
    }
}

// ---------------- K15: final residual add + fused BN3 stats ----------------
__global__ __launch_bounds__(256) void final_kernel(const float* __restrict__ x,
                                                    const float* __restrict__ pre,
                                                    const float* __restrict__ chsum3,
                                                    const float* __restrict__ chsq3,
                                                    const float* __restrict__ g3,
                                                    const float* __restrict__ be3,
                                                    float* __restrict__ out) {
    __shared__ float lsc[256], lsh[256];
    const int t = threadIdx.x;
    {
        const float m = chsum3[t] * (1.0f / (float)M);
        const float var = chsq3[t] * (1.0f / (float)M) - m * m;
        const float rstd = rsqrtf(var + EPS);
        const float sc = rstd * g3[t];
        lsc[t] = sc;
        lsh[t] = be3[t] - m * sc;
    }
    __syncthreads();
    const int i = blockIdx.x * 256 + t;   // float4 index
    const int e = i * 4;
    const int d = e & 255;
    const float4 xv = *(const float4*)(x + e);
    const float4 pv = *(const float4*)(pre + e);
    const float4 sc = *(const float4*)(lsc + d);
    const float4 sh = *(const float4*)(lsh + d);
    float4 o;
    o.x = xv.x + fmaf(pv.x, sc.x, sh.x);
    o.y = xv.y + fmaf(pv.y, sc.y, sh.y);
    o.z = xv.z + fmaf(pv.z, sc.z, sh.z);
    o.w = xv.w + fmaf(pv.w, sc.w, sh.w);
    *(float4*)(out + e) = o;
}

extern "C" void kernel_launch(void* const* d_in, const int* in_sizes, int n_in,
                              void* d_out, int out_size, void* d_ws, size_t ws_size,
                              hipStream_t stream) {
    const float* x    = (const float*)d_in[0];
    const float* w1   = (const float*)d_in[1];
    const float* b1   = (const float*)d_in[2];
    const float* g1   = (const float*)d_in[3];
    const float* be1  = (const float*)d_in[4];
    const float* aw1  = (const float*)d_in[5];
    const float* ab1  = (const float*)d_in[6];
    const float* aw2  = (const float*)d_in[7];
    const float* ab2  = (const float*)d_in[8];
    const float* g2   = (const float*)d_in[9];
    const float* be2  = (const float*)d_in[10];
    const float* caw1 = (const float*)d_in[11];
    const float* caw2 = (const float*)d_in[12];
    const float* pw   = (const float*)d_in[13];
    const float* pb   = (const float*)d_in[14];
    const float* g3   = (const float*)d_in[15];
    const float* be3  = (const float*)d_in[16];
    const float* sw   = (const float*)d_in[17];
    const float* sb   = (const float*)d_in[18];
    float* out = (float*)d_out;
    float* ws = (float*)d_ws;

    float* chsum1  = ws + WS_CHSUM1;
    float* chsq1   = ws + WS_CHSQ1;
    float* gapsum  = ws + WS_GAPSUM;
    float* chsum3  = ws + WS_CHSUM3;
    float* chsq3   = ws + WS_CHSQ3;
    float* chsum2  = ws + WS_CHSUM2;
    float* chsq2   = ws + WS_CHSQ2;
    float* bsum2   = ws + WS_BSUM2;
    u32*   umax2   = (u32*)(ws + WS_UMAX2);
    u32*   umaxn2  = (u32*)(ws + WS_UMAXN2);
    float* scale1  = ws + WS_SCALE1;
    float* shift1  = ws + WS_SHIFT1;
    float* kw      = ws + WS_KW;
    float* scale2  = ws + WS_SCALE2;
    float* shift2  = ws + WS_SHIFT2;
    float* s_att   = ws + WS_SATT;
    float* avg_o   = ws + WS_AVGO;
    float* max_o   = ws + WS_MAXO;
    float* pre     = ws + WS_PRE;
    u16* t1b = (u16*)(ws + WS_T1B);
    u16* t2b = (u16*)(ws + WS_T2B);
    u16* xb  = (u16*)(ws + WS_XB);
    u16* w1b = (u16*)(ws + WS_W1B);
    u16* pwb = (u16*)(ws + WS_PWB);
    u16* yb  = (u16*)(ws + WS_YB);

    // K0: zero accumulators + all casts in one launch
    cvt_all_kernel<<<dim3(2560), 256, 0, stream>>>(x, w1, pw, xb, w1b, pwb, ws);
    // K1: expand GEMM — full-K single-barrier staging (64KB LDS, 2048 blocks)
    gemm1_kernel<<<dim3(C / 64, M / 64), 256, 0, stream>>>(
        xb, w1b, b1, t1b, chsum1, chsq1, gapsum);
    // K4: BN1 stats + gap + dynamic kernel weights (fused)
    dynmlp_kernel<<<dim3(B), 1024, 0, stream>>>(chsum1, chsq1, gapsum, g1, be1,
                                                aw1, ab1, aw2, ab2, scale1, shift1, kw);
    // K5: depthwise conv v3 (LDS-staged rows, 1024 blocks) + GELU -> bf16 t2, BN2 atomics
    dwconv_kernel<<<dim3(4, B * H), 256, 0, stream>>>(t1b, scale1, shift1, kw, t2b,
                                                      chsum2, chsq2, bsum2, umax2, umaxn2);
    // K8: BN2 finalize (O(1)/thread) + channel attention
    chatt_kernel<<<dim3(B), 1024, 0, stream>>>(chsum2, chsq2, bsum2, umax2, umaxn2,
                                               g2, be2, caw1, caw2, scale2, shift2, s_att);
    // K9: y quantize + spatial stats
    yq_kernel<<<dim3(M), 256, 0, stream>>>(t2b, scale2, shift2, s_att, yb, avg_o, max_o);
    // K12: project GEMM — K-unroll x4 + fused 7x7 spatial attention prologue
    gemm2_kernel<<<dim3(D / 64, M / 64), 256, 0, stream>>>(
        yb, pwb, pb, avg_o, max_o, sw, sb, pre, chsum3, chsq3);
    // K15: BN3 stats + final residual add (fused)
    final_kernel<<<dim3((M * D / 4) / 256), 256, 0, stream>>>(x, pre, chsum3, chsq3, g3, be3, out);
}